// Round 9
// baseline (286.315 us; speedup 1.0000x reference)
//
#include <hip/hip_runtime.h>

namespace {

constexpr int HW     = 512 * 512;        // 2^18
constexpr int NCLS   = 26;
constexpr int NPIX   = 4 * HW;           // 1,048,576
constexpr float EPS  = 1e-8f;

__global__ __launch_bounds__(64) void hiera_zero(float* __restrict__ acc) {
  if (threadIdx.x < 3) acc[threadIdx.x] = 0.0f;
}

// 1 pixel/thread. 26 channel loads as inline-asm global_load_dword (saddr
// form): asm outputs are real registers -> compiler cannot rematerialize or
// serialize them (R4 failure), and all 26 stay in flight per wave. Scalar
// base per channel keeps addressing on the SALU pipe.
__global__ __launch_bounds__(256) void hiera_main(
    const float* __restrict__ logits, const int* __restrict__ labels,
    float* __restrict__ acc) {
  constexpr int LP[20] = {0,0,0,1,1,1,2,2,2,3,3,3,4,4,4,5,5,5,5,5};

  const int bimg = blockIdx.x >> 10;            // image index (wave-uniform)
  const int hw0  = (blockIdx.x & 1023) << 8;    // 1024 blocks of 256 px per image
  const float* sbase = logits + (((size_t)bimg * NCLS) << 18) + hw0;  // scalar
  const unsigned voff = threadIdx.x * 4u;       // per-lane byte offset

  const int L = labels[(((size_t)bimg) << 18) + hw0 + threadIdx.x];

  float x[NCLS];
#pragma unroll
  for (int c = 0; c < NCLS; ++c) {
    asm volatile("global_load_dword %0, %1, %2"
                 : "=v"(x[c])
                 : "v"(voff), "s"(sbase + ((size_t)c << 18)));
  }
  asm volatile("s_waitcnt vmcnt(0)" ::: "memory");
  __builtin_amdgcn_sched_barrier(0);            // rule #18: no hoisting past the wait

  float pr[NCLS];
#pragma unroll
  for (int c = 0; c < NCLS; ++c)
    pr[c] = __builtin_amdgcn_rcpf(1.0f + __expf(-x[c]));

  // ---- leaf set (k = 20); BCE logs fused 4-at-a-time: 20 logs -> 5.
  // term in [1e-8, 1+1e-8] -> 4-product >= 1e-32, normal f32. ----
  float cmax[6] = {0.f, 0.f, 0.f, 0.f, 0.f, 0.f};
  float gp[5]   = {1.f, 1.f, 1.f, 1.f, 1.f};
  float se_l = 0.0f, sel_l = 0.0f;
  int parL = -1;
#pragma unroll
  for (int i = 0; i < 20; ++i) {
    const int lp = LP[i];
    const float m  = pr[6 + i];                 // mcma_leaf
    const float mc = fminf(m, pr[lp]);          // mcla_leaf
    cmax[lp] = fmaxf(cmax[lp], m);
    const bool lab = (L == 6 + i);
    gp[i >> 2] *= lab ? (mc + EPS) : (1.0f - m + EPS);
    se_l += __expf(m);                          // m in (0,1): no max-shift needed
    sel_l = lab ? m : sel_l;
    parL  = lab ? lp : parL;
  }
  const float bce_l = -(__logf(gp[0]) + __logf(gp[1]) + __logf(gp[2]) +
                        __logf(gp[3]) + __logf(gp[4]));
  const float lse_l = __logf(se_l);

  // ---- parent set (k = 6); 6 logs -> 2 (3-products >= 1e-24, normal) ----
  float gq0 = 1.0f, gq1 = 1.0f, se_p = 0.0f, sel_p = 0.0f;
#pragma unroll
  for (int q = 0; q < 6; ++q) {
    const float mm = fmaxf(pr[q], cmax[q]);     // mcma_par
    const bool lab = (L == q) || (parL == q);   // exactly one true when valid
    const float term = lab ? (pr[q] + EPS) : (1.0f - mm + EPS);
    if (q < 3) gq0 *= term; else gq1 *= term;
    se_p += __expf(mm);
    sel_p = lab ? mm : sel_p;
  }
  const float bce_p = -(__logf(gq0) + __logf(gq1));
  const float lse_p = __logf(se_p);

  float a_bce = 0.0f, a_ce = 0.0f, a_vd = 0.0f;
  if (L != 26) {
    a_vd  = 1.0f;
    a_bce = bce_l * (1.0f / 20.0f) + bce_p * (1.0f / 6.0f);
    a_ce  = lse_p - sel_p;                      // parent CE (one-hot label)
    if (L >= 6) a_ce += lse_l - sel_l;          // leaf CE only if label is a leaf
  }
  // invalid pixels: BCE/CE numerators 0; CE mean divides by NPIX in finalize.

  // ---- block reduction: wave shuffle -> LDS -> atomics ----
  const int lane = threadIdx.x & 63;
  const int w    = threadIdx.x >> 6;
#pragma unroll
  for (int off = 32; off > 0; off >>= 1) {
    a_bce += __shfl_down(a_bce, off);
    a_ce  += __shfl_down(a_ce,  off);
    a_vd  += __shfl_down(a_vd,  off);
  }
  __shared__ float sred[3][4];
  if (lane == 0) { sred[0][w] = a_bce; sred[1][w] = a_ce; sred[2][w] = a_vd; }
  __syncthreads();
  if (threadIdx.x == 0) {
    atomicAdd(&acc[0], sred[0][0] + sred[0][1] + sred[0][2] + sred[0][3]);
    atomicAdd(&acc[1], sred[1][0] + sred[1][1] + sred[1][2] + sred[1][3]);
    atomicAdd(&acc[2], sred[2][0] + sred[2][1] + sred[2][2] + sred[2][3]);
  }
}

__global__ __launch_bounds__(64) void hiera_final(const float* __restrict__ acc,
                                                  float* __restrict__ out) {
  if (threadIdx.x == 0) {
    const float loss = acc[0] / acc[2];             // already scaled by 1/20, 1/6
    const float ce   = acc[1] * (1.0f / (float)NPIX);
    out[0] = 5.0f * loss + ce;
  }
}

}  // namespace

extern "C" void kernel_launch(void* const* d_in, const int* in_sizes, int n_in,
                              void* d_out, int out_size, void* d_ws, size_t ws_size,
                              hipStream_t stream) {
  const float* logits = (const float*)d_in[0];
  const int*   labels = (const int*)d_in[1];
  float* acc = (float*)d_ws;   // 3 floats
  float* out = (float*)d_out;

  hiera_zero<<<1, 64, 0, stream>>>(acc);
  hiera_main<<<NPIX / 256, 256, 0, stream>>>(logits, labels, acc);  // 4096 blocks
  hiera_final<<<1, 64, 0, stream>>>(acc, out);
}